// Round 10
// baseline (268.652 us; speedup 1.0000x reference)
//
#include <hip/hip_runtime.h>
#include <hip/hip_bf16.h>
#include <math.h>

typedef short bf16x8 __attribute__((ext_vector_type(8)));
typedef float f32x4  __attribute__((ext_vector_type(4)));

struct WC   { float c[13]; };                 // interior composed 13-tap
struct G157 { float g3[3], g5[5], g7[7]; };   // per-level 1-D gaussians

__device__ __forceinline__ unsigned short f2bf(float f) {
  __hip_bfloat16 h = __float2bfloat16(f);     // RNE
  return *reinterpret_cast<unsigned short*>(&h);
}

// zero out + S; block 0 builds per-position composed weight table wtab[256][16]
__global__ __launch_bounds__(256) void zero_k(float* __restrict__ out, float* __restrict__ S,
                                              float* __restrict__ wtab, G157 gw) {
  int i = blockIdx.x * 256 + threadIdx.x;
  if (i < 65536) out[i] = 0.f;
  if (i < 1024) S[i] = 0.f;
  if (blockIdx.x == 0) {
    int g = threadIdx.x;
    float row[13];
    #pragma unroll
    for (int t = 0; t < 13; ++t) row[t] = 0.f;
    #pragma unroll
    for (int di = -3; di <= 3; ++di) {
      int ii = g + di;
      if ((unsigned)ii >= 256u) continue;
      float w7 = gw.g7[di + 3];
      #pragma unroll
      for (int dj = -2; dj <= 2; ++dj) {
        int jj = ii + dj;
        if ((unsigned)jj >= 256u) continue;
        float c2 = w7 * gw.g5[dj + 2];
        #pragma unroll
        for (int dk = -1; dk <= 1; ++dk) {
          int mm = jj + dk;
          if ((unsigned)mm >= 256u) continue;
          row[di + dj + dk + 6] += c2 * gw.g3[dk + 1];
        }
      }
    }
    #pragma unroll
    for (int t = 0; t < 13; ++t) wtab[(g << 4) + t] = row[t];
    wtab[(g << 4) + 13] = 0.f; wtab[(g << 4) + 14] = 0.f; wtab[(g << 4) + 15] = 0.f;
  }
}

// ctx = x - blur(x), bf16 out. v-conv per-column register window (unrolled ring),
// h-conv in 4-cols/lane layout with aligned ds_read_b128; boundary cols handled
// INLINE by lanes q<2 / q>=62 via wl (rb pads + wl zeros make OOB taps harmless).
__global__ __launch_bounds__(256) void ctx_k(const float* __restrict__ x,
                                             unsigned short* __restrict__ ctxb,
                                             const float* __restrict__ wtab,
                                             WC wc) {
  __shared__ __align__(16) float rb[2][4][272];   // v-results: 8 pad | 256 | 8 pad
  __shared__ __align__(16) float xrb[2][4][256];  // x rows (for ctx = x - h)
  __shared__ float wl[96];                        // boundary weight rows 0..5 (x16)

  const int tid = threadIdx.x;
  const int img = blockIdx.x >> 2;
  const int band = blockIdx.x & 3;
  const int y0 = band << 6;
  const float* xg = x + ((size_t)img << 16);
  unsigned short* cgb = ctxb + ((size_t)img << 16);

  if (tid < 96) wl[tid] = wtab[tid];
  if (tid < 128) {  // zero rb pads once
    int bb = (tid >> 6) & 1, rr = (tid >> 4) & 3, pp = tid & 15;
    rb[bb][rr][(pp < 8) ? pp : (256 + pp)] = 0.f;
  }

  // input ring: slot(row) = (row - y0 + 6) mod 24. Init rows y0-6 .. y0+13.
  float win[24];
  #pragma unroll
  for (int i = 0; i < 24; ++i) win[i] = 0.f;
  #pragma unroll
  for (int i = 0; i < 20; ++i) {
    int yy = y0 - 6 + i;
    if ((unsigned)yy < 256u) win[i] = xg[yy * 256 + tid];
  }
  __syncthreads();

  const int g = tid >> 6, q = tid & 63;   // h-phase: wave g -> row, lane q -> cols 4q..4q+3
  const bool hfix = (q < 2) || (q >= 62);

  #pragma unroll
  for (int it = 0; it < 16; ++it) {
    const int y = y0 + 4 * it;
    // prefetch rows y+14..y+17 (2-iteration lookahead); band needs rows up to y0+69
    #pragma unroll
    for (int j = 0; j < 4; ++j) {
      if (4 * it + 14 + j < 70) {
        int yy = y + 14 + j;
        float v = 0.f;
        if (yy < 256) v = xg[yy * 256 + tid];
        win[(4 * it + 20 + j) % 24] = v;
      }
    }
    // vertical conv, 4 rows, per-column (compile-time ring indices)
    float vv[4];
    if (it > 1 && it < 14) {  // rows y0+8..y0+55: always interior
      #pragma unroll
      for (int r = 0; r < 4; ++r) {
        float a = 0.f;
        #pragma unroll
        for (int t = 0; t < 13; ++t) a += wc.c[t] * win[(4 * it + r + t) % 24];
        vv[r] = a;
      }
    } else {
      #pragma unroll
      for (int r = 0; r < 4; ++r) {
        int yr = y + r;
        float a = 0.f;
        if (yr < 6) {
          #pragma unroll
          for (int t = 0; t < 13; ++t) a += wl[(yr << 4) + t] * win[(4 * it + r + t) % 24];
        } else if (yr > 249) {
          #pragma unroll
          for (int t = 0; t < 13; ++t) a += wl[((255 - yr) << 4) + (12 - t)] * win[(4 * it + r + t) % 24];
        } else {
          #pragma unroll
          for (int t = 0; t < 13; ++t) a += wc.c[t] * win[(4 * it + r + t) % 24];
        }
        vv[r] = a;
      }
    }
    const int buf = it & 1;
    #pragma unroll
    for (int r = 0; r < 4; ++r) {
      rb[buf][r][8 + tid] = vv[r];
      xrb[buf][r][tid] = win[(4 * it + 6 + r) % 24];
    }
    __syncthreads();

    // horizontal conv: aligned b128 reads; cols 4q+j use f[2+j .. 14+j]
    const float* hp = &rb[buf][g][4 * q];
    float f[20];
    *(float4*)&f[0]  = *(const float4*)(hp + 0);
    *(float4*)&f[4]  = *(const float4*)(hp + 4);
    *(float4*)&f[8]  = *(const float4*)(hp + 8);
    *(float4*)&f[12] = *(const float4*)(hp + 12);
    *(float4*)&f[16] = *(const float4*)(hp + 16);
    float4 xq = *(const float4*)&xrb[buf][g][4 * q];
    float hh[4];
    {
      float h0 = 0.f, h1 = 0.f, h2 = 0.f, h3 = 0.f;
      #pragma unroll
      for (int t = 0; t < 13; ++t) {
        float w = wc.c[t];
        h0 += w * f[2 + t]; h1 += w * f[3 + t]; h2 += w * f[4 + t]; h3 += w * f[5 + t];
      }
      hh[0] = h0; hh[1] = h1; hh[2] = h2; hh[3] = h3;
    }
    if (hfix) {  // exact boundary cols: wl rows have zeros at OOB taps; rb pads are zero
      #pragma unroll
      for (int j = 0; j < 4; ++j) {
        int col = 4 * q + j;
        if (col < 6) {
          float a = 0.f;
          #pragma unroll
          for (int t = 0; t < 13; ++t) a += wl[(col << 4) + t] * f[2 + j + t];
          hh[j] = a;
        } else if (col > 249) {
          float a = 0.f;
          #pragma unroll
          for (int t = 0; t < 13; ++t) a += wl[((255 - col) << 4) + (12 - t)] * f[2 + j + t];
          hh[j] = a;
        }
      }
    }
    unsigned short s0 = f2bf(xq.x - hh[0]), s1 = f2bf(xq.y - hh[1]);
    unsigned short s2 = f2bf(xq.z - hh[2]), s3 = f2bf(xq.w - hh[3]);
    *(ushort4*)(cgb + (size_t)(y + g) * 256 + 4 * q) = make_ushort4(s0, s1, s2, s3);
  }
}

// MFMA att: per batch b, att = P * C^T, P = exp(C), C = ctx[b] (64 x 65536 bf16).
// S[b,d] accumulated here (each ctx element seen exactly once as an A-fragment).
__global__ __launch_bounds__(256) void att_k(const unsigned short* __restrict__ ctxb,
                                             float* __restrict__ S,
                                             float* __restrict__ attacc) {
  const int t = threadIdx.x;
  const int wv = t >> 6, lane = t & 63;
  const int rw = lane & 15;
  const int kq = lane >> 4;
  const int ci = blockIdx.x;       // 64 chunks of 1024
  const int b = blockIdx.y;        // 16 batches
  const unsigned short* cb = ctxb + ((size_t)b << 22);
  const int n0 = (ci << 10) + (kq << 3);

  const unsigned short* pA = cb + (((size_t)(16 * wv + rw)) << 16) + n0;
  const unsigned short* pB = cb + (((size_t)rw) << 16) + n0;

  f32x4 acc0 = {0.f, 0.f, 0.f, 0.f}, acc1 = acc0, acc2 = acc0, acc3 = acc0;
  float ssum = 0.f;

  #pragma unroll 8
  for (int ks = 0; ks < 1024; ks += 32) {
    bf16x8 av = *(const bf16x8*)(pA + ks);
    bf16x8 ev;
    const unsigned* au = (const unsigned*)&av;
    unsigned* eu = (unsigned*)&ev;
    #pragma unroll
    for (int j = 0; j < 4; ++j) {
      unsigned w = au[j];
      float elo = __expf(__uint_as_float(w << 16));
      float ehi = __expf(__uint_as_float(w & 0xffff0000u));
      ssum += elo + ehi;
      eu[j] = ((unsigned)f2bf(ehi) << 16) | (unsigned)f2bf(elo);
    }
    bf16x8 b0 = *(const bf16x8*)(pB + ks);
    bf16x8 b1 = *(const bf16x8*)(pB + (size_t)(16 << 16) + ks);
    bf16x8 b2 = *(const bf16x8*)(pB + (size_t)(32 << 16) + ks);
    bf16x8 b3 = *(const bf16x8*)(pB + (size_t)(48 << 16) + ks);
    acc0 = __builtin_amdgcn_mfma_f32_16x16x32_bf16(ev, b0, acc0, 0, 0, 0);
    acc1 = __builtin_amdgcn_mfma_f32_16x16x32_bf16(ev, b1, acc1, 0, 0, 0);
    acc2 = __builtin_amdgcn_mfma_f32_16x16x32_bf16(ev, b2, acc2, 0, 0, 0);
    acc3 = __builtin_amdgcn_mfma_f32_16x16x32_bf16(ev, b3, acc3, 0, 0, 0);
  }

  // S row-sum: lanes {rw, rw+16, rw+32, rw+48} hold partials for row 16wv+rw
  ssum += __shfl_xor(ssum, 16);
  ssum += __shfl_xor(ssum, 32);
  if (lane < 16) atomicAdd(&S[(b << 6) + (wv << 4) + rw], ssum);

  // C/D layout: col = lane&15, row = (lane>>4)*4 + reg
  const int dl = kq << 2;
  float* ap = attacc + (((size_t)((b << 6) + (wv << 4) + dl)) << 6) + rw;
  #pragma unroll
  for (int reg = 0; reg < 4; ++reg) {
    atomicAdd(ap + ((size_t)reg << 6) + 0,  acc0[reg]);
    atomicAdd(ap + ((size_t)reg << 6) + 16, acc1[reg]);
    atomicAdd(ap + ((size_t)reg << 6) + 32, acc2[reg]);
    atomicAdd(ap + ((size_t)reg << 6) + 48, acc3[reg]);
  }
}

__global__ __launch_bounds__(256) void fin_k(float* __restrict__ out, const float* __restrict__ S) {
  int i = blockIdx.x * 256 + threadIdx.x;  // 65536 = 16*64*64
  out[i] = out[i] / S[i >> 6];
}

extern "C" void kernel_launch(void* const* d_in, const int* in_sizes, int n_in,
                              void* d_out, int out_size, void* d_ws, size_t ws_size,
                              hipStream_t stream) {
  const float* x = (const float*)d_in[0];
  float* out = (float*)d_out;
  unsigned short* ctxb = (unsigned short*)d_ws;                        // 134 MiB bf16
  float* S    = (float*)((char*)d_ws + (size_t)67108864 * 2);          // 4 KB
  float* wtab = (float*)((char*)d_ws + (size_t)67108864 * 2 + 4096);   // 16 KB
  if (ws_size < (size_t)67108864 * 2 + 4096 + 16384) return;

  // per-level 1-D gaussians in double (matches cv2.getGaussianKernel)
  double gg[3][7];
  double sv = pow(2.0, 1.0 / 3.0);
  for (int lv = 0; lv < 3; ++lv) {
    int k = 2 * lv + 3;
    double sig = 1.6 * pow(sv, lv), sum = 0.0;
    for (int i = 0; i < k; ++i) {
      double a = i - (k - 1) / 2.0;
      gg[lv][i] = exp(-a * a / (2.0 * sig * sig));
      sum += gg[lv][i];
    }
    for (int i = 0; i < k; ++i) gg[lv][i] /= sum;
  }

  G157 gw;
  for (int i = 0; i < 3; ++i) gw.g3[i] = (float)gg[0][i];
  for (int i = 0; i < 5; ++i) gw.g5[i] = (float)gg[1][i];
  for (int i = 0; i < 7; ++i) gw.g7[i] = (float)gg[2][i];

  WC wc;
  {
    double t35[7] = {0};
    for (int i = 0; i < 3; ++i)
      for (int j = 0; j < 5; ++j) t35[i + j] += gg[0][i] * gg[1][j];
    double t357[13] = {0};
    for (int i = 0; i < 7; ++i)
      for (int j = 0; j < 7; ++j) t357[i + j] += t35[i] * gg[2][j];
    for (int t = 0; t < 13; ++t) wc.c[t] = (float)t357[t];
  }

  zero_k<<<dim3(256), dim3(256), 0, stream>>>(out, S, wtab, gw);
  ctx_k<<<dim3(4096), dim3(256), 0, stream>>>(x, ctxb, wtab, wc);
  att_k<<<dim3(64, 16), dim3(256), 0, stream>>>(ctxb, S, out);
  fin_k<<<dim3(256), dim3(256), 0, stream>>>(out, S);
}

// Round 11
// 250.917 us; speedup vs baseline: 1.0707x; 1.0707x over previous
//
#include <hip/hip_runtime.h>
#include <hip/hip_bf16.h>
#include <math.h>

typedef short bf16x8 __attribute__((ext_vector_type(8)));
typedef float f32x4  __attribute__((ext_vector_type(4)));

struct WC   { float c[13]; };                 // interior composed 13-tap
struct G157 { float g3[3], g5[5], g7[7]; };   // per-level 1-D gaussians

__device__ __forceinline__ unsigned short f2bf(float f) {
  __hip_bfloat16 h = __float2bfloat16(f);     // RNE
  return *reinterpret_cast<unsigned short*>(&h);
}

// zero out + S; block 0 builds per-position composed weight table wtab[256][16]
__global__ __launch_bounds__(256) void zero_k(float* __restrict__ out, float* __restrict__ S,
                                              float* __restrict__ wtab, G157 gw) {
  int i = blockIdx.x * 256 + threadIdx.x;
  if (i < 65536) out[i] = 0.f;
  if (i < 1024) S[i] = 0.f;
  if (blockIdx.x == 0) {
    int g = threadIdx.x;
    float row[13];
    #pragma unroll
    for (int t = 0; t < 13; ++t) row[t] = 0.f;
    #pragma unroll
    for (int di = -3; di <= 3; ++di) {
      int ii = g + di;
      if ((unsigned)ii >= 256u) continue;
      float w7 = gw.g7[di + 3];
      #pragma unroll
      for (int dj = -2; dj <= 2; ++dj) {
        int jj = ii + dj;
        if ((unsigned)jj >= 256u) continue;
        float c2 = w7 * gw.g5[dj + 2];
        #pragma unroll
        for (int dk = -1; dk <= 1; ++dk) {
          int mm = jj + dk;
          if ((unsigned)mm >= 256u) continue;
          row[di + dj + dk + 6] += c2 * gw.g3[dk + 1];
        }
      }
    }
    #pragma unroll
    for (int t = 0; t < 13; ++t) wtab[(g << 4) + t] = row[t];
    wtab[(g << 4) + 13] = 0.f; wtab[(g << 4) + 14] = 0.f; wtab[(g << 4) + 15] = 0.f;
  }
}

// ctx = x - blur(x), bf16 out. 128-thread block = 128-col panel x 64-row band.
// v-conv per-column register ring (lanes 0..5 of wave 0 also run the 6-col halo
// ring); h-conv 4 cols/lane from double-buffered LDS (b128). Edge cols fixed in
// a post-pass (round-8 proven; inline fixup predication was a 2x VALU loss).
__global__ __launch_bounds__(128) void ctx_k(const float* __restrict__ x,
                                             unsigned short* __restrict__ ctxb,
                                             const float* __restrict__ wtab,
                                             WC wc) {
  __shared__ __align__(16) float rb[2][4][152];   // v: idx 8+c for panel col c in [-6,133]
  __shared__ __align__(16) float xrb[2][4][128];  // x rows (for ctx = x - h)
  __shared__ float vs[64][12];                    // v at the 12 image-edge cols of this panel
  __shared__ float wl[96];                        // boundary weight rows 0..5 (x16)

  const int tid = threadIdx.x;
  const int bi = blockIdx.x;
  const int px = bi & 1;               // panel: cols px*128 .. +127
  const int band = (bi >> 1) & 3;      // 4 bands of 64 rows
  const int img = bi >> 3;             // 1024 images
  const int y0 = band << 6;
  const int p0 = px << 7;
  const float* xg = x + ((size_t)img << 16);
  unsigned short* cgb = ctxb + ((size_t)img << 16);

  if (tid < 96) wl[tid] = wtab[tid];
  // zero static rb pads: {0,1}, {142..151}, and the image-edge halo side
  for (int u = tid; u < 144; u += 128) {
    int bb = u / 72, rem = u % 72, rr = rem / 18, k = rem % 18;
    int idx = (k < 2) ? k : ((k < 12) ? (140 + k) : (px == 0 ? (2 + k - 12) : (124 + k)));
    rb[bb][rr][idx] = 0.f;
  }

  // own column ring (24 slots): slot(row) = (row - y0 + 6) % 24
  const int cown = p0 + tid;
  float win[24];
  #pragma unroll
  for (int i = 0; i < 24; ++i) win[i] = 0.f;
  #pragma unroll
  for (int i = 0; i < 20; ++i) {
    int yy = y0 - 6 + i;
    if ((unsigned)yy < 256u) win[i] = xg[yy * 256 + cown];
  }
  // halo ring: lanes 0..5 own the 6 in-image halo cols of this panel
  const bool hal = (tid < 6);
  const int hc = (px == 0) ? (128 + tid) : (122 + tid);  // always in [0,256)
  const int hidx = (px == 0) ? (136 + tid) : (2 + tid);  // rb index
  float win2[24];
  #pragma unroll
  for (int i = 0; i < 24; ++i) win2[i] = 0.f;
  if (hal) {
    #pragma unroll
    for (int i = 0; i < 20; ++i) {
      int yy = y0 - 6 + i;
      if ((unsigned)yy < 256u) win2[i] = xg[yy * 256 + hc];
    }
  }
  __syncthreads();

  const bool vsave = (px == 0) ? (tid < 12) : (tid >= 116);
  const int vsidx = (px == 0) ? tid : (tid - 116);
  const int g = tid >> 6, q = tid & 63;
  const int hr = (g << 1) + (q >> 5);   // h-phase row 0..3
  const int m = q & 31;                 // h-phase col-group: cols p0+4m..+3

  #pragma unroll
  for (int it = 0; it < 16; ++it) {
    const int y = y0 + 4 * it;
    // prefetch rows y+14..y+17 (2-iteration lookahead)
    #pragma unroll
    for (int j = 0; j < 4; ++j) {
      if (4 * it + 14 + j < 70) {
        int yy = y + 14 + j;
        float v = 0.f, v2 = 0.f;
        if (yy < 256) {
          v = xg[yy * 256 + cown];
          if (hal) v2 = xg[yy * 256 + hc];
        }
        win[(4 * it + 20 + j) % 24] = v;
        if (hal) win2[(4 * it + 20 + j) % 24] = v2;
      }
    }
    // vertical conv, 4 rows (compile-time ring indices)
    float vv[4], vv2[4];
    if (it > 1 && it < 14) {
      #pragma unroll
      for (int r = 0; r < 4; ++r) {
        float a = 0.f;
        #pragma unroll
        for (int t = 0; t < 13; ++t) a += wc.c[t] * win[(4 * it + r + t) % 24];
        vv[r] = a;
      }
      if (hal) {
        #pragma unroll
        for (int r = 0; r < 4; ++r) {
          float a = 0.f;
          #pragma unroll
          for (int t = 0; t < 13; ++t) a += wc.c[t] * win2[(4 * it + r + t) % 24];
          vv2[r] = a;
        }
      }
    } else {
      #pragma unroll
      for (int r = 0; r < 4; ++r) {
        int yr = y + r;
        float a = 0.f, a2 = 0.f;
        if (yr < 6) {
          #pragma unroll
          for (int t = 0; t < 13; ++t) {
            a += wl[(yr << 4) + t] * win[(4 * it + r + t) % 24];
            a2 += wl[(yr << 4) + t] * win2[(4 * it + r + t) % 24];
          }
        } else if (yr > 249) {
          #pragma unroll
          for (int t = 0; t < 13; ++t) {
            a += wl[((255 - yr) << 4) + (12 - t)] * win[(4 * it + r + t) % 24];
            a2 += wl[((255 - yr) << 4) + (12 - t)] * win2[(4 * it + r + t) % 24];
          }
        } else {
          #pragma unroll
          for (int t = 0; t < 13; ++t) {
            a += wc.c[t] * win[(4 * it + r + t) % 24];
            a2 += wc.c[t] * win2[(4 * it + r + t) % 24];
          }
        }
        vv[r] = a; vv2[r] = a2;
      }
    }
    const int buf = it & 1;
    #pragma unroll
    for (int r = 0; r < 4; ++r) {
      rb[buf][r][8 + tid] = vv[r];
      xrb[buf][r][tid] = win[(4 * it + 6 + r) % 24];
      if (hal) rb[buf][r][hidx] = vv2[r];
    }
    if (vsave) {
      #pragma unroll
      for (int r = 0; r < 4; ++r) vs[4 * it + r][vsidx] = vv[r];
    }
    __syncthreads();

    // horizontal conv: row hr, cols p0+4m..+3; aligned b128 reads
    const float* hp = &rb[buf][hr][4 * m];
    float f[20];
    *(float4*)&f[0]  = *(const float4*)(hp + 0);
    *(float4*)&f[4]  = *(const float4*)(hp + 4);
    *(float4*)&f[8]  = *(const float4*)(hp + 8);
    *(float4*)&f[12] = *(const float4*)(hp + 12);
    *(float4*)&f[16] = *(const float4*)(hp + 16);
    float4 xq = *(const float4*)&xrb[buf][hr][4 * m];
    float h0 = 0.f, h1 = 0.f, h2 = 0.f, h3 = 0.f;
    #pragma unroll
    for (int t = 0; t < 13; ++t) {
      float w = wc.c[t];
      h0 += w * f[2 + t]; h1 += w * f[3 + t]; h2 += w * f[4 + t]; h3 += w * f[5 + t];
    }
    unsigned short s0 = f2bf(xq.x - h0), s1 = f2bf(xq.y - h1);
    unsigned short s2 = f2bf(xq.z - h2), s3 = f2bf(xq.w - h3);
    *(ushort4*)(cgb + (size_t)(y + hr) * 256 + p0 + 4 * m) = make_ushort4(s0, s1, s2, s3);
  }

  __syncthreads();
  // post-pass: exact h-conv for this panel's 6 image-edge cols x 64 rows
  #pragma unroll
  for (int k = 0; k < 3; ++k) {
    int e = k * 128 + tid;           // 384 elements
    int row = e / 6;
    int ce = e - row * 6;
    float h = 0.f;
    int col;
    if (px == 0) {
      col = ce;                       // cols 0..5; vs holds v at cols 0..11
      #pragma unroll
      for (int t = 0; t < 13; ++t) {
        int vc = col - 6 + t;
        if (vc >= 0) h += wl[(col << 4) + t] * vs[row][vc];
      }
    } else {
      col = 250 + ce;                 // cols 250..255; vs holds v at cols 244..255
      #pragma unroll
      for (int t = 0; t < 13; ++t) {
        int vc = col - 6 + t;
        if (vc < 256) h += wl[((255 - col) << 4) + (12 - t)] * vs[row][vc - 244];
      }
    }
    int yrow = y0 + row;
    float xval = xg[yrow * 256 + col];
    cgb[yrow * 256 + col] = f2bf(xval - h);
  }
}

// MFMA att: per batch b, att = P * C^T, P = exp(C), C = ctx[b] (64 x 65536 bf16).
// S[b,d] accumulated here (each ctx element seen exactly once as an A-fragment).
__global__ __launch_bounds__(256) void att_k(const unsigned short* __restrict__ ctxb,
                                             float* __restrict__ S,
                                             float* __restrict__ attacc) {
  const int t = threadIdx.x;
  const int wv = t >> 6, lane = t & 63;
  const int rw = lane & 15;
  const int kq = lane >> 4;
  const int ci = blockIdx.x;       // 64 chunks of 1024
  const int b = blockIdx.y;        // 16 batches
  const unsigned short* cb = ctxb + ((size_t)b << 22);
  const int n0 = (ci << 10) + (kq << 3);

  const unsigned short* pA = cb + (((size_t)(16 * wv + rw)) << 16) + n0;
  const unsigned short* pB = cb + (((size_t)rw) << 16) + n0;

  f32x4 acc0 = {0.f, 0.f, 0.f, 0.f}, acc1 = acc0, acc2 = acc0, acc3 = acc0;
  float ssum = 0.f;

  #pragma unroll 8
  for (int ks = 0; ks < 1024; ks += 32) {
    bf16x8 av = *(const bf16x8*)(pA + ks);
    bf16x8 ev;
    const unsigned* au = (const unsigned*)&av;
    unsigned* eu = (unsigned*)&ev;
    #pragma unroll
    for (int j = 0; j < 4; ++j) {
      unsigned w = au[j];
      float elo = __expf(__uint_as_float(w << 16));
      float ehi = __expf(__uint_as_float(w & 0xffff0000u));
      ssum += elo + ehi;
      eu[j] = ((unsigned)f2bf(ehi) << 16) | (unsigned)f2bf(elo);
    }
    bf16x8 b0 = *(const bf16x8*)(pB + ks);
    bf16x8 b1 = *(const bf16x8*)(pB + (size_t)(16 << 16) + ks);
    bf16x8 b2 = *(const bf16x8*)(pB + (size_t)(32 << 16) + ks);
    bf16x8 b3 = *(const bf16x8*)(pB + (size_t)(48 << 16) + ks);
    acc0 = __builtin_amdgcn_mfma_f32_16x16x32_bf16(ev, b0, acc0, 0, 0, 0);
    acc1 = __builtin_amdgcn_mfma_f32_16x16x32_bf16(ev, b1, acc1, 0, 0, 0);
    acc2 = __builtin_amdgcn_mfma_f32_16x16x32_bf16(ev, b2, acc2, 0, 0, 0);
    acc3 = __builtin_amdgcn_mfma_f32_16x16x32_bf16(ev, b3, acc3, 0, 0, 0);
  }

  // S row-sum: lanes {rw, rw+16, rw+32, rw+48} hold partials for row 16wv+rw
  ssum += __shfl_xor(ssum, 16);
  ssum += __shfl_xor(ssum, 32);
  if (lane < 16) atomicAdd(&S[(b << 6) + (wv << 4) + rw], ssum);

  // C/D layout: col = lane&15, row = (lane>>4)*4 + reg
  const int dl = kq << 2;
  float* ap = attacc + (((size_t)((b << 6) + (wv << 4) + dl)) << 6) + rw;
  #pragma unroll
  for (int reg = 0; reg < 4; ++reg) {
    atomicAdd(ap + ((size_t)reg << 6) + 0,  acc0[reg]);
    atomicAdd(ap + ((size_t)reg << 6) + 16, acc1[reg]);
    atomicAdd(ap + ((size_t)reg << 6) + 32, acc2[reg]);
    atomicAdd(ap + ((size_t)reg << 6) + 48, acc3[reg]);
  }
}

__global__ __launch_bounds__(256) void fin_k(float* __restrict__ out, const float* __restrict__ S) {
  int i = blockIdx.x * 256 + threadIdx.x;  // 65536 = 16*64*64
  out[i] = out[i] / S[i >> 6];
}

extern "C" void kernel_launch(void* const* d_in, const int* in_sizes, int n_in,
                              void* d_out, int out_size, void* d_ws, size_t ws_size,
                              hipStream_t stream) {
  const float* x = (const float*)d_in[0];
  float* out = (float*)d_out;
  unsigned short* ctxb = (unsigned short*)d_ws;                        // 134 MiB bf16
  float* S    = (float*)((char*)d_ws + (size_t)67108864 * 2);          // 4 KB
  float* wtab = (float*)((char*)d_ws + (size_t)67108864 * 2 + 4096);   // 16 KB
  if (ws_size < (size_t)67108864 * 2 + 4096 + 16384) return;

  // per-level 1-D gaussians in double (matches cv2.getGaussianKernel)
  double gg[3][7];
  double sv = pow(2.0, 1.0 / 3.0);
  for (int lv = 0; lv < 3; ++lv) {
    int k = 2 * lv + 3;
    double sig = 1.6 * pow(sv, lv), sum = 0.0;
    for (int i = 0; i < k; ++i) {
      double a = i - (k - 1) / 2.0;
      gg[lv][i] = exp(-a * a / (2.0 * sig * sig));
      sum += gg[lv][i];
    }
    for (int i = 0; i < k; ++i) gg[lv][i] /= sum;
  }

  G157 gw;
  for (int i = 0; i < 3; ++i) gw.g3[i] = (float)gg[0][i];
  for (int i = 0; i < 5; ++i) gw.g5[i] = (float)gg[1][i];
  for (int i = 0; i < 7; ++i) gw.g7[i] = (float)gg[2][i];

  WC wc;
  {
    double t35[7] = {0};
    for (int i = 0; i < 3; ++i)
      for (int j = 0; j < 5; ++j) t35[i + j] += gg[0][i] * gg[1][j];
    double t357[13] = {0};
    for (int i = 0; i < 7; ++i)
      for (int j = 0; j < 7; ++j) t357[i + j] += t35[i] * gg[2][j];
    for (int t = 0; t < 13; ++t) wc.c[t] = (float)t357[t];
  }

  zero_k<<<dim3(256), dim3(256), 0, stream>>>(out, S, wtab, gw);
  ctx_k<<<dim3(8192), dim3(128), 0, stream>>>(x, ctxb, wtab, wc);
  att_k<<<dim3(64, 16), dim3(256), 0, stream>>>(ctxb, S, out);
  fin_k<<<dim3(256), dim3(256), 0, stream>>>(out, S);
}

// Round 12
// 218.269 us; speedup vs baseline: 1.2308x; 1.1496x over previous
//
#include <hip/hip_runtime.h>
#include <hip/hip_bf16.h>
#include <math.h>

typedef short bf16x8 __attribute__((ext_vector_type(8)));
typedef float f32x4  __attribute__((ext_vector_type(4)));

struct WC   { float c[13]; };                 // interior composed 13-tap
struct G157 { float g3[3], g5[5], g7[7]; };   // per-level 1-D gaussians

__device__ __forceinline__ unsigned short f2bf(float f) {
  __hip_bfloat16 h = __float2bfloat16(f);     // RNE
  return *reinterpret_cast<unsigned short*>(&h);
}

// zero out + S; block 0 builds per-position composed weight table wtab[256][16]
__global__ __launch_bounds__(256) void zero_k(float* __restrict__ out, float* __restrict__ S,
                                              float* __restrict__ wtab, G157 gw) {
  int i = blockIdx.x * 256 + threadIdx.x;
  if (i < 65536) out[i] = 0.f;
  if (i < 1024) S[i] = 0.f;
  if (blockIdx.x == 0) {
    int g = threadIdx.x;
    float row[13];
    #pragma unroll
    for (int t = 0; t < 13; ++t) row[t] = 0.f;
    #pragma unroll
    for (int di = -3; di <= 3; ++di) {
      int ii = g + di;
      if ((unsigned)ii >= 256u) continue;
      float w7 = gw.g7[di + 3];
      #pragma unroll
      for (int dj = -2; dj <= 2; ++dj) {
        int jj = ii + dj;
        if ((unsigned)jj >= 256u) continue;
        float c2 = w7 * gw.g5[dj + 2];
        #pragma unroll
        for (int dk = -1; dk <= 1; ++dk) {
          int mm = jj + dk;
          if ((unsigned)mm >= 256u) continue;
          row[di + dj + dk + 6] += c2 * gw.g3[dk + 1];
        }
      }
    }
    #pragma unroll
    for (int t = 0; t < 13; ++t) wtab[(g << 4) + t] = row[t];
    wtab[(g << 4) + 13] = 0.f; wtab[(g << 4) + 14] = 0.f; wtab[(g << 4) + 15] = 0.f;
  }
}

// ctx = x - blur(x), bf16 out. Wave-local structure: one wave = one full 256-col
// row; lane q owns cols 4q..4q+3 (float4). 16-deep register ring for x rows;
// v-conv in regs; v->h exchange via the wave's PRIVATE LDS row (same-wave DS is
// in-order => NO barriers in the main loop). Row-boundary weights: wave-uniform
// branches. Edge cols: evs capture + wave-local post-pass.
__global__ __launch_bounds__(256, 3) void ctx_k(const float* __restrict__ x,
                                                unsigned short* __restrict__ ctxb,
                                                const float* __restrict__ wtab,
                                                WC wc) {
  __shared__ __align__(16) float vb[4][272];      // per-wave: [8 pad][256][8 pad]
  __shared__ __align__(16) float evs[4][16][24];  // per-wave v at cols 0..11/244..255
  __shared__ float wl[96];                        // boundary weight rows 0..5 (x16)

  const int tid = threadIdx.x;
  const int w = tid >> 6, q = tid & 63;
  const int img = blockIdx.x >> 2, band = blockIdx.x & 3;
  const int r0 = (band << 6) + (w << 4);   // this wave's 16 rows: r0..r0+15
  const int c0 = q << 2;
  const float* xg = x + ((size_t)img << 16);
  unsigned short* cgb = ctxb + ((size_t)img << 16);

  if (tid < 96) wl[tid] = wtab[tid];
  if (q < 2) {  // zero this wave's pads once (wave-local)
    *(float4*)&vb[w][q << 2] = make_float4(0.f, 0.f, 0.f, 0.f);
    *(float4*)&vb[w][264 + (q << 2)] = make_float4(0.f, 0.f, 0.f, 0.f);
  }
  __syncthreads();  // wl visibility only

  // register ring: slot(row) = (row - r0 + 6) & 15. Init rows r0-6..r0+8.
  float4 ring[16];
  #pragma unroll
  for (int i = 0; i < 15; ++i) {
    int yy = r0 - 6 + i;
    float4 v = make_float4(0.f, 0.f, 0.f, 0.f);
    if ((unsigned)yy < 256u) v = *(const float4*)(xg + yy * 256 + c0);
    ring[i] = v;
  }
  ring[15] = make_float4(0.f, 0.f, 0.f, 0.f);

  #pragma unroll
  for (int rr = 0; rr < 16; ++rr) {
    // prefetch row r0+rr+9 -> slot (rr+15)&15 (3-iteration lookahead)
    {
      int yy = r0 + rr + 9;
      float4 v = make_float4(0.f, 0.f, 0.f, 0.f);
      if (yy < 256) v = *(const float4*)(xg + yy * 256 + c0);
      ring[(rr + 15) & 15] = v;
    }
    const int y = r0 + rr;

    // vertical conv (wave-uniform row-regime branches; alt paths only where reachable)
    float ax = 0.f, ay = 0.f, az = 0.f, aw = 0.f;
    if (rr >= 6 && rr <= 9) {         // always interior
      #pragma unroll
      for (int t = 0; t < 13; ++t) {
        float4 s = ring[(rr + t) & 15];
        float wv = wc.c[t];
        ax += wv * s.x; ay += wv * s.y; az += wv * s.z; aw += wv * s.w;
      }
    } else if (rr < 6) {              // possible top boundary (only r0==0)
      if (y >= 6) {
        #pragma unroll
        for (int t = 0; t < 13; ++t) {
          float4 s = ring[(rr + t) & 15];
          float wv = wc.c[t];
          ax += wv * s.x; ay += wv * s.y; az += wv * s.z; aw += wv * s.w;
        }
      } else {
        #pragma unroll
        for (int t = 0; t < 13; ++t) {
          float4 s = ring[(rr + t) & 15];
          float wv = wl[(y << 4) + t];
          ax += wv * s.x; ay += wv * s.y; az += wv * s.z; aw += wv * s.w;
        }
      }
    } else {                          // rr > 9: possible bottom boundary (only r0==240)
      if (y <= 249) {
        #pragma unroll
        for (int t = 0; t < 13; ++t) {
          float4 s = ring[(rr + t) & 15];
          float wv = wc.c[t];
          ax += wv * s.x; ay += wv * s.y; az += wv * s.z; aw += wv * s.w;
        }
      } else {
        #pragma unroll
        for (int t = 0; t < 13; ++t) {
          float4 s = ring[(rr + t) & 15];
          float wv = wl[((255 - y) << 4) + (12 - t)];
          ax += wv * s.x; ay += wv * s.y; az += wv * s.z; aw += wv * s.w;
        }
      }
    }

    // publish v to this wave's LDS row (+ evs edge capture); same-wave => ordered
    float4 v4 = make_float4(ax, ay, az, aw);
    *(float4*)&vb[w][8 + c0] = v4;
    if (q < 3)       *(float4*)&evs[w][rr][c0] = v4;             // cols 0..11
    else if (q >= 61) *(float4*)&evs[w][rr][12 + ((q - 61) << 2)] = v4;  // cols 244..255

    // horizontal conv: 5 aligned b128 reads; cols c0+j use f[2+j..14+j]
    const float* hp = &vb[w][c0];
    float f[20];
    *(float4*)&f[0]  = *(const float4*)(hp + 0);
    *(float4*)&f[4]  = *(const float4*)(hp + 4);
    *(float4*)&f[8]  = *(const float4*)(hp + 8);
    *(float4*)&f[12] = *(const float4*)(hp + 12);
    *(float4*)&f[16] = *(const float4*)(hp + 16);
    float h0 = 0.f, h1 = 0.f, h2 = 0.f, h3 = 0.f;
    #pragma unroll
    for (int t = 0; t < 13; ++t) {
      float wv = wc.c[t];
      h0 += wv * f[2 + t]; h1 += wv * f[3 + t]; h2 += wv * f[4 + t]; h3 += wv * f[5 + t];
    }
    float4 xq = ring[(rr + 6) & 15];   // own x row, own cols (no LDS)
    unsigned short s0 = f2bf(xq.x - h0), s1 = f2bf(xq.y - h1);
    unsigned short s2 = f2bf(xq.z - h2), s3 = f2bf(xq.w - h3);
    *(ushort4*)(cgb + (size_t)y * 256 + c0) = make_ushort4(s0, s1, s2, s3);
  }

  // wave-local post-pass: exact h at the 12 edge cols x this wave's 16 rows.
  // wl rows carry zeros at OOB taps; clamp evs index so 0*garbage can't be NaN.
  #pragma unroll
  for (int k = 0; k < 3; ++k) {
    int e = (k << 6) + q;              // 0..191 = 16 rows x 12 cols
    int row = e / 12;
    int ce = e - row * 12;
    int y = r0 + row;
    int col = (ce < 6) ? ce : (244 + ce);   // {0..5, 250..255}
    float h = 0.f;
    if (ce < 6) {
      #pragma unroll
      for (int t = 0; t < 13; ++t) {
        int vc = col - 6 + t;
        int vi = (vc < 0) ? 0 : vc;         // weight is 0 when vc<0
        h += wl[(col << 4) + t] * evs[w][row][vi];
      }
    } else {
      #pragma unroll
      for (int t = 0; t < 13; ++t) {
        int vc = col - 6 + t;
        int vi = (vc > 255 ? 255 : vc) - 232;  // weight is 0 when vc>255
        h += wl[((255 - col) << 4) + (12 - t)] * evs[w][row][vi];
      }
    }
    float xv = xg[(size_t)y * 256 + col];
    cgb[(size_t)y * 256 + col] = f2bf(xv - h);
  }
}

// MFMA att: per batch b, att = P * C^T, P = exp(C), C = ctx[b] (64 x 65536 bf16).
// S[b,d] accumulated here (each ctx element seen exactly once as an A-fragment).
__global__ __launch_bounds__(256) void att_k(const unsigned short* __restrict__ ctxb,
                                             float* __restrict__ S,
                                             float* __restrict__ attacc) {
  const int t = threadIdx.x;
  const int wv = t >> 6, lane = t & 63;
  const int rw = lane & 15;
  const int kq = lane >> 4;
  const int ci = blockIdx.x;       // 64 chunks of 1024
  const int b = blockIdx.y;        // 16 batches
  const unsigned short* cb = ctxb + ((size_t)b << 22);
  const int n0 = (ci << 10) + (kq << 3);

  const unsigned short* pA = cb + (((size_t)(16 * wv + rw)) << 16) + n0;
  const unsigned short* pB = cb + (((size_t)rw) << 16) + n0;

  f32x4 acc0 = {0.f, 0.f, 0.f, 0.f}, acc1 = acc0, acc2 = acc0, acc3 = acc0;
  float ssum = 0.f;

  #pragma unroll 8
  for (int ks = 0; ks < 1024; ks += 32) {
    bf16x8 av = *(const bf16x8*)(pA + ks);
    bf16x8 ev;
    const unsigned* au = (const unsigned*)&av;
    unsigned* eu = (unsigned*)&ev;
    #pragma unroll
    for (int j = 0; j < 4; ++j) {
      unsigned ww = au[j];
      float elo = __expf(__uint_as_float(ww << 16));
      float ehi = __expf(__uint_as_float(ww & 0xffff0000u));
      ssum += elo + ehi;
      eu[j] = ((unsigned)f2bf(ehi) << 16) | (unsigned)f2bf(elo);
    }
    bf16x8 b0 = *(const bf16x8*)(pB + ks);
    bf16x8 b1 = *(const bf16x8*)(pB + (size_t)(16 << 16) + ks);
    bf16x8 b2 = *(const bf16x8*)(pB + (size_t)(32 << 16) + ks);
    bf16x8 b3 = *(const bf16x8*)(pB + (size_t)(48 << 16) + ks);
    acc0 = __builtin_amdgcn_mfma_f32_16x16x32_bf16(ev, b0, acc0, 0, 0, 0);
    acc1 = __builtin_amdgcn_mfma_f32_16x16x32_bf16(ev, b1, acc1, 0, 0, 0);
    acc2 = __builtin_amdgcn_mfma_f32_16x16x32_bf16(ev, b2, acc2, 0, 0, 0);
    acc3 = __builtin_amdgcn_mfma_f32_16x16x32_bf16(ev, b3, acc3, 0, 0, 0);
  }

  // S row-sum: lanes {rw, rw+16, rw+32, rw+48} hold partials for row 16wv+rw
  ssum += __shfl_xor(ssum, 16);
  ssum += __shfl_xor(ssum, 32);
  if (lane < 16) atomicAdd(&S[(b << 6) + (wv << 4) + rw], ssum);

  // C/D layout: col = lane&15, row = (lane>>4)*4 + reg
  const int dl = kq << 2;
  float* ap = attacc + (((size_t)((b << 6) + (wv << 4) + dl)) << 6) + rw;
  #pragma unroll
  for (int reg = 0; reg < 4; ++reg) {
    atomicAdd(ap + ((size_t)reg << 6) + 0,  acc0[reg]);
    atomicAdd(ap + ((size_t)reg << 6) + 16, acc1[reg]);
    atomicAdd(ap + ((size_t)reg << 6) + 32, acc2[reg]);
    atomicAdd(ap + ((size_t)reg << 6) + 48, acc3[reg]);
  }
}

__global__ __launch_bounds__(256) void fin_k(float* __restrict__ out, const float* __restrict__ S) {
  int i = blockIdx.x * 256 + threadIdx.x;  // 65536 = 16*64*64
  out[i] = out[i] / S[i >> 6];
}

extern "C" void kernel_launch(void* const* d_in, const int* in_sizes, int n_in,
                              void* d_out, int out_size, void* d_ws, size_t ws_size,
                              hipStream_t stream) {
  const float* x = (const float*)d_in[0];
  float* out = (float*)d_out;
  unsigned short* ctxb = (unsigned short*)d_ws;                        // 134 MiB bf16
  float* S    = (float*)((char*)d_ws + (size_t)67108864 * 2);          // 4 KB
  float* wtab = (float*)((char*)d_ws + (size_t)67108864 * 2 + 4096);   // 16 KB
  if (ws_size < (size_t)67108864 * 2 + 4096 + 16384) return;

  // per-level 1-D gaussians in double (matches cv2.getGaussianKernel)
  double gg[3][7];
  double sv = pow(2.0, 1.0 / 3.0);
  for (int lv = 0; lv < 3; ++lv) {
    int k = 2 * lv + 3;
    double sig = 1.6 * pow(sv, lv), sum = 0.0;
    for (int i = 0; i < k; ++i) {
      double a = i - (k - 1) / 2.0;
      gg[lv][i] = exp(-a * a / (2.0 * sig * sig));
      sum += gg[lv][i];
    }
    for (int i = 0; i < k; ++i) gg[lv][i] /= sum;
  }

  G157 gw;
  for (int i = 0; i < 3; ++i) gw.g3[i] = (float)gg[0][i];
  for (int i = 0; i < 5; ++i) gw.g5[i] = (float)gg[1][i];
  for (int i = 0; i < 7; ++i) gw.g7[i] = (float)gg[2][i];

  WC wc;
  {
    double t35[7] = {0};
    for (int i = 0; i < 3; ++i)
      for (int j = 0; j < 5; ++j) t35[i + j] += gg[0][i] * gg[1][j];
    double t357[13] = {0};
    for (int i = 0; i < 7; ++i)
      for (int j = 0; j < 7; ++j) t357[i + j] += t35[i] * gg[2][j];
    for (int t = 0; t < 13; ++t) wc.c[t] = (float)t357[t];
  }

  zero_k<<<dim3(256), dim3(256), 0, stream>>>(out, S, wtab, gw);
  ctx_k<<<dim3(4096), dim3(256), 0, stream>>>(x, ctxb, wtab, wc);
  att_k<<<dim3(64, 16), dim3(256), 0, stream>>>(ctxb, S, out);
  fin_k<<<dim3(256), dim3(256), 0, stream>>>(out, S);
}